// Round 4
// baseline (1260.865 us; speedup 1.0000x reference)
//
#include <hip/hip_runtime.h>
#include <hip/hip_bf16.h>

#define DEV __device__ __forceinline__

typedef __attribute__((ext_vector_type(8))) short bf16x8;
typedef __attribute__((ext_vector_type(8))) unsigned short u16x8;
typedef __attribute__((ext_vector_type(4))) unsigned short u16x4;
typedef __attribute__((ext_vector_type(4))) float f32x4;

#define GRID 256
#define BLOCK 512

DEV unsigned short f2bf(float f) {
  return __builtin_bit_cast(unsigned short, __float2bfloat16(f));
}
DEV float bf2f(unsigned short h) { return __uint_as_float(((unsigned int)h) << 16); }

// LDS swizzle for BK=64 tiles (128B rows): XOR 16B-slot with (row&7).
DEV int swz(int row, int byteoff) { return row * 128 + (byteoff ^ ((row & 7) << 4)); }

// ---------------------------------------------------------------- grid barrier
// Sense-reversing, device-scope. All GRID blocks must call it (no early returns).
DEV void gridbar(unsigned* cnt, unsigned* gen) {
  __syncthreads();
  if (threadIdx.x == 0) {
    __threadfence();  // release my block's plain stores
    unsigned g = __hip_atomic_load(gen, __ATOMIC_RELAXED, __HIP_MEMORY_SCOPE_AGENT);
    unsigned old = __hip_atomic_fetch_add(cnt, 1u, __ATOMIC_ACQ_REL, __HIP_MEMORY_SCOPE_AGENT);
    if (old == GRID - 1) {
      __hip_atomic_store(cnt, 0u, __ATOMIC_RELAXED, __HIP_MEMORY_SCOPE_AGENT);
      __hip_atomic_fetch_add(gen, 1u, __ATOMIC_ACQ_REL, __HIP_MEMORY_SCOPE_AGENT);
    } else {
      while (__hip_atomic_load(gen, __ATOMIC_ACQUIRE, __HIP_MEMORY_SCOPE_AGENT) == g)
        __builtin_amdgcn_s_sleep(2);
    }
  }
  __syncthreads();
}

// ---------------------------------------------------------------- cvt fp32->bf16 (8 segments)
struct CvtJobs { const float* s[8]; unsigned short* d[8]; float* df[8]; int n[8]; };
__global__ void cvtw_kernel(CvtJobs J) {
  const int seg = blockIdx.y;
  const float* __restrict__ src = J.s[seg];
  unsigned short* __restrict__ dst = J.d[seg];
  float* __restrict__ dstf = J.df[seg];
  const int n = J.n[seg];
  long i = ((long)blockIdx.x * blockDim.x + threadIdx.x) * 8;
  long stride = (long)gridDim.x * blockDim.x * 8;
  for (; i < n; i += stride) {
    f32x4 a = *(const f32x4*)(src + i);
    f32x4 b = *(const f32x4*)(src + i + 4);
    u16x8 o;
    o[0] = f2bf(a[0]); o[1] = f2bf(a[1]); o[2] = f2bf(a[2]); o[3] = f2bf(a[3]);
    o[4] = f2bf(b[0]); o[5] = f2bf(b[1]); o[6] = f2bf(b[2]); o[7] = f2bf(b[3]);
    *(u16x8*)(dst + i) = o;
    if (dstf) { *(f32x4*)(dstf + i) = a; *(f32x4*)(dstf + i + 4) = b; }
  }
}

// ---------------------------------------------------------------- GEMM stage (device, 512 threads)
// Y[m,n] = act( sum_k X[m,k]*W[n,k] + bias[n] [+ res[m,n]] ). 8 waves as 2x4.
// Tile BMxBN, BK=64, reg-staged double-buffered pipeline, batched (NB) over z.
template <int BM, int BN, int ACT, int OUTF32, int OUTBF, int RES>
DEV void gemm_stage(char* SM, int bid, int t,
                    const unsigned short* __restrict__ X, const unsigned short* __restrict__ W,
                    const float* __restrict__ bias, const float* __restrict__ res,
                    float* __restrict__ Yf, unsigned short* __restrict__ Ybf,
                    int M, int N, int K, int NB, long xbs, long wbs, long bbs, long ybs) {
  constexpr int ABY = BM * 64 * 2, BBY = BN * 64 * 2;
  constexpr int MI = BM / 32, NI = BN / 64;
  constexpr int CB = (BN * 8) / BLOCK;  // B chunks per thread (1 or 2)
  char* Asb = SM;
  char* Bsb = SM + 2 * ABY;
  const int lane = t & 63, wv = t >> 6, wr = wv >> 2, wc = wv & 3;
  const int tilesN = N / BN, tpb = (M / BM) * tilesN;
  const int ntile = NB * tpb;
  const int rowA = t >> 3, slotA = t & 7;  // valid if t < BM*8
  int rowB[CB], slotB[CB];
#pragma unroll
  for (int c = 0; c < CB; ++c) { int id = c * BLOCK + t; rowB[c] = id >> 3; slotB[c] = id & 7; }

  for (int tile = bid; tile < ntile; tile += GRID) {
    const int z = tile / tpb, rem = tile % tpb, tm = rem / tilesN, tn = rem % tilesN;
    const unsigned short* Xp = X + (long)z * xbs + (long)tm * BM * K;
    const unsigned short* Wp = W + (long)z * wbs + (long)tn * BN * K;
    f32x4 acc[MI][NI];
#pragma unroll
    for (int mi = 0; mi < MI; ++mi)
#pragma unroll
      for (int ni = 0; ni < NI; ++ni) acc[mi][ni] = f32x4{0.f, 0.f, 0.f, 0.f};

    u16x8 ra, rbv[CB];
    auto load = [&](int kt) {
      if (BM * 8 == BLOCK || t < BM * 8)
        ra = *(const u16x8*)(Xp + (long)rowA * K + kt + slotA * 8);
#pragma unroll
      for (int c = 0; c < CB; ++c)
        rbv[c] = *(const u16x8*)(Wp + (long)rowB[c] * K + kt + slotB[c] * 8);
    };
    auto store = [&](int cur) {
      if (BM * 8 == BLOCK || t < BM * 8)
        *(u16x8*)(Asb + cur * ABY + swz(rowA, slotA * 16)) = ra;
#pragma unroll
      for (int c = 0; c < CB; ++c)
        *(u16x8*)(Bsb + cur * BBY + swz(rowB[c], slotB[c] * 16)) = rbv[c];
    };

    const int NT = K >> 6;
    load(0);
    store(0);
    load(64);
    __syncthreads();
    for (int ki = 0; ki < NT; ++ki) {
      const int cur = ki & 1;
      if (ki + 1 < NT) store(cur ^ 1);
      if (ki + 2 < NT) load((ki + 2) << 6);
#pragma unroll
      for (int kk = 0; kk < 2; ++kk) {
        const int kb = kk * 64 + ((lane >> 4) << 4);
        bf16x8 af[MI], bfv[NI];
#pragma unroll
        for (int mi = 0; mi < MI; ++mi)
          af[mi] = *(const bf16x8*)(Asb + cur * ABY + swz(wr * (BM / 2) + mi * 16 + (lane & 15), kb));
#pragma unroll
        for (int ni = 0; ni < NI; ++ni)
          bfv[ni] = *(const bf16x8*)(Bsb + cur * BBY + swz(wc * (BN / 4) + ni * 16 + (lane & 15), kb));
#pragma unroll
        for (int mi = 0; mi < MI; ++mi)
#pragma unroll
          for (int ni = 0; ni < NI; ++ni)
            acc[mi][ni] = __builtin_amdgcn_mfma_f32_16x16x32_bf16(af[mi], bfv[ni], acc[mi][ni], 0, 0, 0);
      }
      __syncthreads();
    }
    // epilogue
#pragma unroll
    for (int ni = 0; ni < NI; ++ni) {
      const int gn = tn * BN + wc * (BN / 4) + ni * 16 + (lane & 15);
      const float bv = bias[(long)z * bbs + gn];
#pragma unroll
      for (int mi = 0; mi < MI; ++mi) {
#pragma unroll
        for (int rr = 0; rr < 4; ++rr) {
          const int gm = tm * BM + wr * (BM / 2) + mi * 16 + ((lane >> 4) << 2) + rr;
          float v = acc[mi][ni][rr] + bv;
          if (RES) v += res[(long)gm * N + gn];
          if (ACT) v = fmaxf(v, 0.f);
          const long o = (long)z * ybs + (long)gm * N + gn;
          if (OUTF32) Yf[o] = v;
          if (OUTBF) Ybf[o] = f2bf(v);
        }
      }
    }
    __syncthreads();
  }
}

// ---------------------------------------------------------------- LN stage (device)
// rows 1024 over 256 blocks: 4 rows/block, one per wave (waves 0..3).
DEV void ln_stage(int bid, int t, const float* __restrict__ in,
                  const float* __restrict__ g, const float* __restrict__ b,
                  float* __restrict__ outf, unsigned short* __restrict__ outbf, int writef) {
  const int lane = t & 63, wv = t >> 6;
  if (wv < 4) {
    const int row = bid * 4 + wv;
    const float* p = in + (long)row * 512 + lane * 8;
    f32x4 a = *(const f32x4*)p;
    f32x4 c = *(const f32x4*)(p + 4);
    float s = a[0] + a[1] + a[2] + a[3] + c[0] + c[1] + c[2] + c[3];
    float q = a[0]*a[0] + a[1]*a[1] + a[2]*a[2] + a[3]*a[3] +
              c[0]*c[0] + c[1]*c[1] + c[2]*c[2] + c[3]*c[3];
#pragma unroll
    for (int msk = 32; msk; msk >>= 1) { s += __shfl_xor(s, msk, 64); q += __shfl_xor(q, msk, 64); }
    const float mean = s * (1.f / 512.f);
    const float var = q * (1.f / 512.f) - mean * mean;
    const float inv = rsqrtf(var + 1e-5f);
    const float* gp = g + lane * 8;
    const float* bp = b + lane * 8;
    float o[8];
#pragma unroll
    for (int j = 0; j < 4; ++j) o[j] = (a[j] - mean) * inv * gp[j] + bp[j];
#pragma unroll
    for (int j = 0; j < 4; ++j) o[4 + j] = (c[j] - mean) * inv * gp[4 + j] + bp[4 + j];
    if (writef) {
      f32x4 w0 = {o[0], o[1], o[2], o[3]}, w1 = {o[4], o[5], o[6], o[7]};
      *(f32x4*)(outf + (long)row * 512 + lane * 8) = w0;
      *(f32x4*)(outf + (long)row * 512 + lane * 8 + 4) = w1;
    }
    u16x8 ob;
#pragma unroll
    for (int j = 0; j < 8; ++j) ob[j] = f2bf(o[j]);
    *(u16x8*)(outbf + (long)row * 512 + lane * 8) = ob;
  }
}

// ---------------------------------------------------------------- attention stage (device)
// 256 blocks: block = (s, half-of-heads). qkv t1:(1024,1536); out ao:(1024,512) bf16.
DEV void attn_stage(char* SM, int bid, int t, const unsigned short* __restrict__ qkv,
                    unsigned short* __restrict__ ao) {
  float* P = (float*)SM;  // 256 floats [hh][l][m]
  const int s = bid >> 1, hg = bid & 1;
  if (t < 256) {
    const int hh = t >> 6, l = (t >> 3) & 7, m = t & 7;
    const int h = hg * 4 + hh;
    const unsigned short* qp = qkv + (long)(l * 128 + s) * 1536 + h * 64;
    const unsigned short* kp = qkv + (long)(m * 128 + s) * 1536 + 512 + h * 64;
    float acc = 0.f;
#pragma unroll
    for (int c = 0; c < 64; c += 8) {
      u16x8 q8 = *(const u16x8*)(qp + c);
      u16x8 k8 = *(const u16x8*)(kp + c);
#pragma unroll
      for (int j = 0; j < 8; ++j) acc += bf2f(q8[j]) * bf2f(k8[j]);
    }
    P[t] = acc * 0.125f;  // 1/sqrt(64)
  }
  __syncthreads();
  if (t < 32) {
    const int base = t * 8;
    float mx = -1e30f;
#pragma unroll
    for (int m = 0; m < 8; ++m) mx = fmaxf(mx, P[base + m]);
    float e[8], sum = 0.f;
#pragma unroll
    for (int m = 0; m < 8; ++m) { e[m] = expf(P[base + m] - mx); sum += e[m]; }
    const float inv = 1.f / sum;
#pragma unroll
    for (int m = 0; m < 8; ++m) P[base + m] = e[m] * inv;
  }
  __syncthreads();
  // PV: thread -> (l, hh, d4)
  const int l = t >> 6, hh = (t >> 4) & 3, d4 = (t & 15) * 4;
  const int h = hg * 4 + hh;
  float o[4] = {0.f, 0.f, 0.f, 0.f};
#pragma unroll
  for (int m = 0; m < 8; ++m) {
    const float p = P[hh * 64 + l * 8 + m];
    const unsigned short* vp = qkv + (long)(m * 128 + s) * 1536 + 1024 + h * 64 + d4;
#pragma unroll
    for (int dd = 0; dd < 4; ++dd) o[dd] += p * bf2f(vp[dd]);
  }
  u16x4 pk;
#pragma unroll
  for (int dd = 0; dd < 4; ++dd) pk[dd] = f2bf(o[dd]);
  *(u16x4*)(ao + (long)(l * 128 + s) * 512 + h * 64 + d4) = pk;
}

// ---------------------------------------------------------------- fused persistent kernel
struct Params {
  const float *attn_in_b, *attn_out_b, *ln1_w, *ln1_b, *ln2_w, *ln2_b,
              *ff1_b, *ff2_b, *fln_w, *fln_b, *mlp_b0, *mlp_b1, *mlp_b2;
  const unsigned short *wq, *wo, *wf1, *wf2, *wm0, *wm1, *wm2;
  float *h, *t2, *hf4;
  unsigned short *hbf, *t1, *ao, *z1, *z2, *hb4;
  unsigned* sync;
};

__global__ __launch_bounds__(BLOCK, 1) void fused_kernel(Params P) {
  __shared__ __align__(16) char SM[49152];
  const int bid = blockIdx.x, t = threadIdx.x;
  unsigned* cnt = P.sync;
  unsigned* gen = P.sync + 1;

  for (int L = 0; L < 3; ++L) {
    // qkv: (1024x1536) = 192 tiles of 64x128
    gemm_stage<64, 128, 0, 0, 1, 0>(SM, bid, t, P.hbf, P.wq + (long)L * 1536 * 512,
                                    P.attn_in_b + L * 1536, nullptr, nullptr, P.t1,
                                    1024, 1536, 512, 1, 0, 0, 0, 0);
    gridbar(cnt, gen);
    attn_stage(SM, bid, t, P.t1, P.ao);
    gridbar(cnt, gen);
    // outproj + residual: 256 tiles of 32x64 -> t2 f32
    gemm_stage<32, 64, 0, 1, 0, 1>(SM, bid, t, P.ao, P.wo + (long)L * 512 * 512,
                                   P.attn_out_b + L * 512, P.h, P.t2, nullptr,
                                   1024, 512, 512, 1, 0, 0, 0, 0);
    gridbar(cnt, gen);
    ln_stage(bid, t, P.t2, P.ln1_w + L * 512, P.ln1_b + L * 512, P.h, P.hbf, 1);
    gridbar(cnt, gen);
    // ff1 relu: (1024x2048) = 256 tiles of 64x128
    gemm_stage<64, 128, 1, 0, 1, 0>(SM, bid, t, P.hbf, P.wf1 + (long)L * 2048 * 512,
                                    P.ff1_b + L * 2048, nullptr, nullptr, P.t1,
                                    1024, 2048, 512, 1, 0, 0, 0, 0);
    gridbar(cnt, gen);
    // ff2 + residual: K=2048
    gemm_stage<32, 64, 0, 1, 0, 1>(SM, bid, t, P.t1, P.wf2 + (long)L * 512 * 2048,
                                   P.ff2_b + L * 512, P.h, P.t2, nullptr,
                                   1024, 512, 2048, 1, 0, 0, 0, 0);
    gridbar(cnt, gen);
    ln_stage(bid, t, P.t2, P.ln2_w + L * 512, P.ln2_b + L * 512, P.h, P.hbf, 1);
    gridbar(cnt, gen);
  }
  // final encoder LN: h -> hbf only
  ln_stage(bid, t, P.h, P.fln_w, P.fln_b, nullptr, P.hbf, 0);
  gridbar(cnt, gen);
  // head MLPs, z-batched over 4 heads: 256 tiles each of 64x128
  gemm_stage<64, 128, 1, 0, 1, 0>(SM, bid, t, P.hbf, P.wm0, P.mlp_b0, nullptr, nullptr, P.z1,
                                  1024, 512, 512, 4, 0, 512 * 512, 512, 1024 * 512);
  gridbar(cnt, gen);
  gemm_stage<64, 128, 1, 0, 1, 0>(SM, bid, t, P.z1, P.wm1, P.mlp_b1, nullptr, nullptr, P.z2,
                                  1024, 512, 512, 4, 1024 * 512, 512 * 512, 512, 1024 * 512);
  gridbar(cnt, gen);
  gemm_stage<64, 128, 0, 1, 1, 0>(SM, bid, t, P.z2, P.wm2, P.mlp_b2, nullptr, P.hf4, P.hb4,
                                  1024, 512, 512, 4, 1024 * 512, 512 * 512, 512, 1024 * 512);
}

// ---------------------------------------------------------------- phase C (unchanged, validated)
__global__ __launch_bounds__(256) void phasec_kernel(const float* __restrict__ subp,
                                                     const unsigned short* __restrict__ objbf,
                                                     const float* __restrict__ vsub,
                                                     const float* __restrict__ vobj,
                                                     float* __restrict__ out) {
  constexpr int ABY = 128 * 64 * 2;
  __shared__ __align__(16) char SMEM[67584];
  char* Asb = SMEM;
  char* Bsb = SMEM + 2 * ABY;
  float* Wl = (float*)(SMEM + 4 * ABY);
  const int t = threadIdx.x;
  const int i = blockIdx.x, b = blockIdx.y;
  const long base_bi = ((long)b * 128 + i) * 512;
  for (int d = t; d < 512; d += 256) Wl[d] = vsub[base_bi + d] * vobj[base_bi + d];

  const int lane = t & 63, wv = t >> 6;
  const int wr = wv >> 1, wc = wv & 1;
  f32x4 acc[4][4] = {};

  int row[4], slot[4];
#pragma unroll
  for (int c = 0; c < 4; ++c) { int id = c * 256 + t; row[c] = id >> 3; slot[c] = id & 7; }

  f32x4 fa[4][2];
  u16x8 rb[4];
  auto load = [&](int kt) {
#pragma unroll
    for (int c = 0; c < 4; ++c) {
      const long g = ((long)b * 128 + row[c]) * 512 + kt + slot[c] * 8;
      fa[c][0] = *(const f32x4*)(subp + g);
      fa[c][1] = *(const f32x4*)(subp + g + 4);
      rb[c] = *(const u16x8*)(objbf + g);
    }
  };
  auto store = [&](int cur, int ktd) {
#pragma unroll
    for (int c = 0; c < 4; ++c) {
      const float* wp = Wl + ktd + slot[c] * 8;
      f32x4 w0 = *(const f32x4*)wp;
      f32x4 w1 = *(const f32x4*)(wp + 4);
      u16x8 oa;
      oa[0] = f2bf(fa[c][0][0] * w0[0]); oa[1] = f2bf(fa[c][0][1] * w0[1]);
      oa[2] = f2bf(fa[c][0][2] * w0[2]); oa[3] = f2bf(fa[c][0][3] * w0[3]);
      oa[4] = f2bf(fa[c][1][0] * w1[0]); oa[5] = f2bf(fa[c][1][1] * w1[1]);
      oa[6] = f2bf(fa[c][1][2] * w1[2]); oa[7] = f2bf(fa[c][1][3] * w1[3]);
      *(u16x8*)(Asb + cur * ABY + swz(row[c], slot[c] * 16)) = oa;
      *(u16x8*)(Bsb + cur * ABY + swz(row[c], slot[c] * 16)) = rb[c];
    }
  };

  __syncthreads();
  load(0);
  store(0, 0);
  load(64);
  __syncthreads();
  for (int ki = 0; ki < 8; ++ki) {
    const int cur = ki & 1;
    if (ki + 1 < 8) store(cur ^ 1, (ki + 1) * 64);
    if (ki + 2 < 8) load((ki + 2) * 64);
#pragma unroll
    for (int kk = 0; kk < 2; ++kk) {
      const int kb = kk * 64 + ((lane >> 4) << 4);
      bf16x8 af[4], bfv[4];
#pragma unroll
      for (int mi = 0; mi < 4; ++mi)
        af[mi] = *(const bf16x8*)(Asb + cur * ABY + swz(wr * 64 + mi * 16 + (lane & 15), kb));
#pragma unroll
      for (int ni = 0; ni < 4; ++ni)
        bfv[ni] = *(const bf16x8*)(Bsb + cur * ABY + swz(wc * 64 + ni * 16 + (lane & 15), kb));
#pragma unroll
      for (int mi = 0; mi < 4; ++mi)
#pragma unroll
        for (int ni = 0; ni < 4; ++ni)
          acc[mi][ni] = __builtin_amdgcn_mfma_f32_16x16x32_bf16(af[mi], bfv[ni], acc[mi][ni], 0, 0, 0);
    }
    __syncthreads();
  }
  float* C = (float*)SMEM;
#pragma unroll
  for (int mi = 0; mi < 4; ++mi)
#pragma unroll
    for (int rr = 0; rr < 4; ++rr) {
      const int j = wr * 64 + mi * 16 + ((lane >> 4) << 2) + rr;
      float* crow = C + j * 132 + wc * 64 + (lane & 15);
#pragma unroll
      for (int ni = 0; ni < 4; ++ni) crow[ni * 16] = acc[mi][ni][rr];
    }
  __syncthreads();
  float* ob = out + ((long)b * 128 + i) * 128 * 128;
  const int cc = (t & 31) * 4, jb = (t >> 5) * 16;
#pragma unroll
  for (int q = 0; q < 16; ++q) {
    const int j = jb + q;
    f32x4 v = *(const f32x4*)(C + j * 132 + cc);
    *(f32x4*)(ob + (long)j * 128 + cc) = v;
  }
}

// ---------------------------------------------------------------- launch
extern "C" void kernel_launch(void* const* d_in, const int* in_sizes, int n_in, void* d_out,
                              int out_size, void* d_ws, size_t ws_size, hipStream_t stream) {
  const float* x          = (const float*)d_in[0];
  const float* attn_in_w  = (const float*)d_in[1];
  const float* attn_in_b  = (const float*)d_in[2];
  const float* attn_out_w = (const float*)d_in[3];
  const float* attn_out_b = (const float*)d_in[4];
  const float* ln1_w = (const float*)d_in[5];
  const float* ln1_b = (const float*)d_in[6];
  const float* ln2_w = (const float*)d_in[7];
  const float* ln2_b = (const float*)d_in[8];
  const float* ff1_w = (const float*)d_in[9];
  const float* ff1_b = (const float*)d_in[10];
  const float* ff2_w = (const float*)d_in[11];
  const float* ff2_b = (const float*)d_in[12];
  const float* fln_w = (const float*)d_in[13];
  const float* fln_b = (const float*)d_in[14];
  const float* mlp_w0 = (const float*)d_in[15];
  const float* mlp_b0 = (const float*)d_in[16];
  const float* mlp_w1 = (const float*)d_in[17];
  const float* mlp_b1 = (const float*)d_in[18];
  const float* mlp_w2 = (const float*)d_in[19];
  const float* mlp_b2 = (const float*)d_in[20];
  float* out = (float*)d_out;
  (void)in_sizes; (void)n_in; (void)out_size; (void)ws_size;

  char* ws = (char*)d_ws;
  size_t off = 0;
  auto alloc = [&](size_t bytes) -> void* {
    void* p = (void*)(ws + off);
    off += (bytes + 255) & ~(size_t)255;
    return p;
  };
  unsigned* syncp     = (unsigned*)alloc(256);
  unsigned short* wq  = (unsigned short*)alloc((size_t)3 * 1536 * 512 * 2);
  unsigned short* wo  = (unsigned short*)alloc((size_t)3 * 512 * 512 * 2);
  unsigned short* wf1 = (unsigned short*)alloc((size_t)3 * 2048 * 512 * 2);
  unsigned short* wf2 = (unsigned short*)alloc((size_t)3 * 512 * 2048 * 2);
  unsigned short* wm0 = (unsigned short*)alloc((size_t)4 * 512 * 512 * 2);
  unsigned short* wm1 = (unsigned short*)alloc((size_t)4 * 512 * 512 * 2);
  unsigned short* wm2 = (unsigned short*)alloc((size_t)4 * 512 * 512 * 2);
  float* h            = (float*)alloc((size_t)1024 * 512 * 4);
  unsigned short* hbf = (unsigned short*)alloc((size_t)1024 * 512 * 2);
  unsigned short* t1  = (unsigned short*)alloc((size_t)1024 * 2048 * 2);
  float* t2           = (float*)alloc((size_t)1024 * 512 * 4);
  unsigned short* ao  = (unsigned short*)alloc((size_t)1024 * 512 * 2);
  unsigned short* z1  = (unsigned short*)alloc((size_t)4 * 1024 * 512 * 2);
  unsigned short* z2  = (unsigned short*)alloc((size_t)4 * 1024 * 512 * 2);
  float* hf4          = (float*)alloc((size_t)4 * 1024 * 512 * 4);
  unsigned short* hb4 = (unsigned short*)alloc((size_t)4 * 1024 * 512 * 2);

  hipMemsetAsync(syncp, 0, 8, stream);

  CvtJobs J;
  for (int k = 0; k < 8; ++k) J.df[k] = nullptr;
  J.s[0] = attn_in_w;  J.d[0] = wq;  J.n[0] = 3 * 1536 * 512;
  J.s[1] = attn_out_w; J.d[1] = wo;  J.n[1] = 3 * 512 * 512;
  J.s[2] = ff1_w;      J.d[2] = wf1; J.n[2] = 3 * 2048 * 512;
  J.s[3] = ff2_w;      J.d[3] = wf2; J.n[3] = 3 * 512 * 2048;
  J.s[4] = mlp_w0;     J.d[4] = wm0; J.n[4] = 4 * 512 * 512;
  J.s[5] = mlp_w1;     J.d[5] = wm1; J.n[5] = 4 * 512 * 512;
  J.s[6] = mlp_w2;     J.d[6] = wm2; J.n[6] = 4 * 512 * 512;
  J.s[7] = x;          J.d[7] = hbf; J.n[7] = 1024 * 512; J.df[7] = h;
  cvtw_kernel<<<dim3(512, 8), 256, 0, stream>>>(J);

  Params P;
  P.attn_in_b = attn_in_b; P.attn_out_b = attn_out_b;
  P.ln1_w = ln1_w; P.ln1_b = ln1_b; P.ln2_w = ln2_w; P.ln2_b = ln2_b;
  P.ff1_b = ff1_b; P.ff2_b = ff2_b; P.fln_w = fln_w; P.fln_b = fln_b;
  P.mlp_b0 = mlp_b0; P.mlp_b1 = mlp_b1; P.mlp_b2 = mlp_b2;
  P.wq = wq; P.wo = wo; P.wf1 = wf1; P.wf2 = wf2;
  P.wm0 = wm0; P.wm1 = wm1; P.wm2 = wm2;
  P.h = h; P.t2 = t2; P.hf4 = hf4;
  P.hbf = hbf; P.t1 = t1; P.ao = ao; P.z1 = z1; P.z2 = z2; P.hb4 = hb4;
  P.sync = syncp;
  fused_kernel<<<GRID, BLOCK, 0, stream>>>(P);

  phasec_kernel<<<dim3(128, 8), 256, 0, stream>>>(
      hf4, hb4 + 1 * 1024 * 512, hf4 + 2L * 1024 * 512, hf4 + 3L * 1024 * 512, out);
}

// Round 6
// 1084.456 us; speedup vs baseline: 1.1627x; 1.1627x over previous
//
#include <hip/hip_runtime.h>
#include <hip/hip_bf16.h>
#include <hip/hip_cooperative_groups.h>

namespace cg = cooperative_groups;

#define DEV __device__ __forceinline__

typedef __attribute__((ext_vector_type(8))) short bf16x8;
typedef __attribute__((ext_vector_type(8))) unsigned short u16x8;
typedef __attribute__((ext_vector_type(4))) unsigned short u16x4;
typedef __attribute__((ext_vector_type(4))) float f32x4;

#define GRID 256
#define BLOCK 512

DEV unsigned short f2bf(float f) {
  return __builtin_bit_cast(unsigned short, __float2bfloat16(f));
}
DEV float bf2f(unsigned short h) { return __uint_as_float(((unsigned int)h) << 16); }

// LDS swizzle for BK=64 tiles (128B rows): XOR 16B-slot with (row&7).
DEV int swz(int row, int byteoff) { return row * 128 + (byteoff ^ ((row & 7) << 4)); }

// ---------------------------------------------------------------- cvt fp32->bf16 (8 segments)
struct CvtJobs { const float* s[8]; unsigned short* d[8]; float* df[8]; int n[8]; };
__global__ void cvtw_kernel(CvtJobs J) {
  const int seg = blockIdx.y;
  const float* __restrict__ src = J.s[seg];
  unsigned short* __restrict__ dst = J.d[seg];
  float* __restrict__ dstf = J.df[seg];
  const int n = J.n[seg];
  long i = ((long)blockIdx.x * blockDim.x + threadIdx.x) * 8;
  long stride = (long)gridDim.x * blockDim.x * 8;
  for (; i < n; i += stride) {
    f32x4 a = *(const f32x4*)(src + i);
    f32x4 b = *(const f32x4*)(src + i + 4);
    u16x8 o;
    o[0] = f2bf(a[0]); o[1] = f2bf(a[1]); o[2] = f2bf(a[2]); o[3] = f2bf(a[3]);
    o[4] = f2bf(b[0]); o[5] = f2bf(b[1]); o[6] = f2bf(b[2]); o[7] = f2bf(b[3]);
    *(u16x8*)(dst + i) = o;
    if (dstf) { *(f32x4*)(dstf + i) = a; *(f32x4*)(dstf + i + 4) = b; }
  }
}

// ---------------------------------------------------------------- GEMM stage (device, 512 threads)
// Y[m,n] = act( sum_k X[m,k]*W[n,k] + bias[n] [+ res[m,n]] ). 8 waves as 2x4.
// Tile BMxBN, BK=64, reg-staged double-buffered pipeline, batched (NB) over z.
template <int BM, int BN, int ACT, int OUTF32, int OUTBF, int RES>
DEV void gemm_stage(char* SM, int bid, int t,
                    const unsigned short* __restrict__ X, const unsigned short* __restrict__ W,
                    const float* __restrict__ bias, const float* __restrict__ res,
                    float* __restrict__ Yf, unsigned short* __restrict__ Ybf,
                    int M, int N, int K, int NB, long xbs, long wbs, long bbs, long ybs) {
  constexpr int ABY = BM * 64 * 2, BBY = BN * 64 * 2;
  constexpr int MI = BM / 32, NI = BN / 64;
  constexpr int CB = (BN * 8) / BLOCK;  // B chunks per thread (1 or 2)
  char* Asb = SM;
  char* Bsb = SM + 2 * ABY;
  const int lane = t & 63, wv = t >> 6, wr = wv >> 2, wc = wv & 3;
  const int tilesN = N / BN, tpb = (M / BM) * tilesN;
  const int ntile = NB * tpb;
  const int rowA = t >> 3, slotA = t & 7;  // valid if t < BM*8
  int rowB[CB], slotB[CB];
#pragma unroll
  for (int c = 0; c < CB; ++c) { int id = c * BLOCK + t; rowB[c] = id >> 3; slotB[c] = id & 7; }

  for (int tile = bid; tile < ntile; tile += GRID) {
    const int z = tile / tpb, rem = tile % tpb, tm = rem / tilesN, tn = rem % tilesN;
    const unsigned short* Xp = X + (long)z * xbs + (long)tm * BM * K;
    const unsigned short* Wp = W + (long)z * wbs + (long)tn * BN * K;
    f32x4 acc[MI][NI];
#pragma unroll
    for (int mi = 0; mi < MI; ++mi)
#pragma unroll
      for (int ni = 0; ni < NI; ++ni) acc[mi][ni] = f32x4{0.f, 0.f, 0.f, 0.f};

    u16x8 ra, rbv[CB];
    auto load = [&](int kt) {
      if (BM * 8 == BLOCK || t < BM * 8)
        ra = *(const u16x8*)(Xp + (long)rowA * K + kt + slotA * 8);
#pragma unroll
      for (int c = 0; c < CB; ++c)
        rbv[c] = *(const u16x8*)(Wp + (long)rowB[c] * K + kt + slotB[c] * 8);
    };
    auto store = [&](int cur) {
      if (BM * 8 == BLOCK || t < BM * 8)
        *(u16x8*)(Asb + cur * ABY + swz(rowA, slotA * 16)) = ra;
#pragma unroll
      for (int c = 0; c < CB; ++c)
        *(u16x8*)(Bsb + cur * BBY + swz(rowB[c], slotB[c] * 16)) = rbv[c];
    };

    const int NT = K >> 6;
    load(0);
    store(0);
    load(64);
    __syncthreads();
    for (int ki = 0; ki < NT; ++ki) {
      const int cur = ki & 1;
      if (ki + 1 < NT) store(cur ^ 1);
      if (ki + 2 < NT) load((ki + 2) << 6);
#pragma unroll
      for (int kk = 0; kk < 2; ++kk) {
        const int kb = kk * 64 + ((lane >> 4) << 4);
        bf16x8 af[MI], bfv[NI];
#pragma unroll
        for (int mi = 0; mi < MI; ++mi)
          af[mi] = *(const bf16x8*)(Asb + cur * ABY + swz(wr * (BM / 2) + mi * 16 + (lane & 15), kb));
#pragma unroll
        for (int ni = 0; ni < NI; ++ni)
          bfv[ni] = *(const bf16x8*)(Bsb + cur * BBY + swz(wc * (BN / 4) + ni * 16 + (lane & 15), kb));
#pragma unroll
        for (int mi = 0; mi < MI; ++mi)
#pragma unroll
          for (int ni = 0; ni < NI; ++ni)
            acc[mi][ni] = __builtin_amdgcn_mfma_f32_16x16x32_bf16(af[mi], bfv[ni], acc[mi][ni], 0, 0, 0);
      }
      __syncthreads();
    }
    // epilogue
#pragma unroll
    for (int ni = 0; ni < NI; ++ni) {
      const int gn = tn * BN + wc * (BN / 4) + ni * 16 + (lane & 15);
      const float bv = bias[(long)z * bbs + gn];
#pragma unroll
      for (int mi = 0; mi < MI; ++mi) {
#pragma unroll
        for (int rr = 0; rr < 4; ++rr) {
          const int gm = tm * BM + wr * (BM / 2) + mi * 16 + ((lane >> 4) << 2) + rr;
          float v = acc[mi][ni][rr] + bv;
          if (RES) v += res[(long)gm * N + gn];
          if (ACT) v = fmaxf(v, 0.f);
          const long o = (long)z * ybs + (long)gm * N + gn;
          if (OUTF32) Yf[o] = v;
          if (OUTBF) Ybf[o] = f2bf(v);
        }
      }
    }
    __syncthreads();
  }
}

// ---------------------------------------------------------------- LN stage (device)
// rows 1024 over 256 blocks: 4 rows/block, one per wave (waves 0..3).
DEV void ln_stage(int bid, int t, const float* __restrict__ in,
                  const float* __restrict__ g, const float* __restrict__ b,
                  float* __restrict__ outf, unsigned short* __restrict__ outbf, int writef) {
  const int lane = t & 63, wv = t >> 6;
  if (wv < 4) {
    const int row = bid * 4 + wv;
    const float* p = in + (long)row * 512 + lane * 8;
    f32x4 a = *(const f32x4*)p;
    f32x4 c = *(const f32x4*)(p + 4);
    float s = a[0] + a[1] + a[2] + a[3] + c[0] + c[1] + c[2] + c[3];
    float q = a[0]*a[0] + a[1]*a[1] + a[2]*a[2] + a[3]*a[3] +
              c[0]*c[0] + c[1]*c[1] + c[2]*c[2] + c[3]*c[3];
#pragma unroll
    for (int msk = 32; msk; msk >>= 1) { s += __shfl_xor(s, msk, 64); q += __shfl_xor(q, msk, 64); }
    const float mean = s * (1.f / 512.f);
    const float var = q * (1.f / 512.f) - mean * mean;
    const float inv = rsqrtf(var + 1e-5f);
    const float* gp = g + lane * 8;
    const float* bp = b + lane * 8;
    float o[8];
#pragma unroll
    for (int j = 0; j < 4; ++j) o[j] = (a[j] - mean) * inv * gp[j] + bp[j];
#pragma unroll
    for (int j = 0; j < 4; ++j) o[4 + j] = (c[j] - mean) * inv * gp[4 + j] + bp[4 + j];
    if (writef) {
      f32x4 w0 = {o[0], o[1], o[2], o[3]}, w1 = {o[4], o[5], o[6], o[7]};
      *(f32x4*)(outf + (long)row * 512 + lane * 8) = w0;
      *(f32x4*)(outf + (long)row * 512 + lane * 8 + 4) = w1;
    }
    u16x8 ob;
#pragma unroll
    for (int j = 0; j < 8; ++j) ob[j] = f2bf(o[j]);
    *(u16x8*)(outbf + (long)row * 512 + lane * 8) = ob;
  }
}

// ---------------------------------------------------------------- attention stage (device)
// 256 blocks: block = (s, half-of-heads). qkv t1:(1024,1536); out ao:(1024,512) bf16.
DEV void attn_stage(char* SM, int bid, int t, const unsigned short* __restrict__ qkv,
                    unsigned short* __restrict__ ao) {
  float* P = (float*)SM;  // 256 floats [hh][l][m]
  const int s = bid >> 1, hg = bid & 1;
  if (t < 256) {
    const int hh = t >> 6, l = (t >> 3) & 7, m = t & 7;
    const int h = hg * 4 + hh;
    const unsigned short* qp = qkv + (long)(l * 128 + s) * 1536 + h * 64;
    const unsigned short* kp = qkv + (long)(m * 128 + s) * 1536 + 512 + h * 64;
    float acc = 0.f;
#pragma unroll
    for (int c = 0; c < 64; c += 8) {
      u16x8 q8 = *(const u16x8*)(qp + c);
      u16x8 k8 = *(const u16x8*)(kp + c);
#pragma unroll
      for (int j = 0; j < 8; ++j) acc += bf2f(q8[j]) * bf2f(k8[j]);
    }
    P[t] = acc * 0.125f;  // 1/sqrt(64)
  }
  __syncthreads();
  if (t < 32) {
    const int base = t * 8;
    float mx = -1e30f;
#pragma unroll
    for (int m = 0; m < 8; ++m) mx = fmaxf(mx, P[base + m]);
    float e[8], sum = 0.f;
#pragma unroll
    for (int m = 0; m < 8; ++m) { e[m] = expf(P[base + m] - mx); sum += e[m]; }
    const float inv = 1.f / sum;
#pragma unroll
    for (int m = 0; m < 8; ++m) P[base + m] = e[m] * inv;
  }
  __syncthreads();
  // PV: thread -> (l, hh, d4)
  const int l = t >> 6, hh = (t >> 4) & 3, d4 = (t & 15) * 4;
  const int h = hg * 4 + hh;
  float o[4] = {0.f, 0.f, 0.f, 0.f};
#pragma unroll
  for (int m = 0; m < 8; ++m) {
    const float p = P[hh * 64 + l * 8 + m];
    const unsigned short* vp = qkv + (long)(m * 128 + s) * 1536 + 1024 + h * 64 + d4;
#pragma unroll
    for (int dd = 0; dd < 4; ++dd) o[dd] += p * bf2f(vp[dd]);
  }
  u16x4 pk;
#pragma unroll
  for (int dd = 0; dd < 4; ++dd) pk[dd] = f2bf(o[dd]);
  *(u16x4*)(ao + (long)(l * 128 + s) * 512 + h * 64 + d4) = pk;
}

// ---------------------------------------------------------------- fused persistent kernel
struct Params {
  const float *attn_in_b, *attn_out_b, *ln1_w, *ln1_b, *ln2_w, *ln2_b,
              *ff1_b, *ff2_b, *fln_w, *fln_b, *mlp_b0, *mlp_b1, *mlp_b2;
  const unsigned short *wq, *wo, *wf1, *wf2, *wm0, *wm1, *wm2;
  float *h, *t2, *hf4;
  unsigned short *hbf, *t1, *ao, *z1, *z2, *hb4;
};

__global__ __launch_bounds__(BLOCK, 1) void fused_kernel(Params P) {
  __shared__ __align__(16) char SM[49152];
  const int bid = blockIdx.x, t = threadIdx.x;
  cg::grid_group grid = cg::this_grid();

  for (int L = 0; L < 3; ++L) {
    // qkv: (1024x1536) = 192 tiles of 64x128
    gemm_stage<64, 128, 0, 0, 1, 0>(SM, bid, t, P.hbf, P.wq + (long)L * 1536 * 512,
                                    P.attn_in_b + L * 1536, nullptr, nullptr, P.t1,
                                    1024, 1536, 512, 1, 0, 0, 0, 0);
    grid.sync();
    attn_stage(SM, bid, t, P.t1, P.ao);
    grid.sync();
    // outproj + residual: 256 tiles of 32x64 -> t2 f32
    gemm_stage<32, 64, 0, 1, 0, 1>(SM, bid, t, P.ao, P.wo + (long)L * 512 * 512,
                                   P.attn_out_b + L * 512, P.h, P.t2, nullptr,
                                   1024, 512, 512, 1, 0, 0, 0, 0);
    grid.sync();
    ln_stage(bid, t, P.t2, P.ln1_w + L * 512, P.ln1_b + L * 512, P.h, P.hbf, 1);
    grid.sync();
    // ff1 relu: (1024x2048) = 256 tiles of 64x128
    gemm_stage<64, 128, 1, 0, 1, 0>(SM, bid, t, P.hbf, P.wf1 + (long)L * 2048 * 512,
                                    P.ff1_b + L * 2048, nullptr, nullptr, P.t1,
                                    1024, 2048, 512, 1, 0, 0, 0, 0);
    grid.sync();
    // ff2 + residual: K=2048
    gemm_stage<32, 64, 0, 1, 0, 1>(SM, bid, t, P.t1, P.wf2 + (long)L * 512 * 2048,
                                   P.ff2_b + L * 512, P.h, P.t2, nullptr,
                                   1024, 512, 2048, 1, 0, 0, 0, 0);
    grid.sync();
    ln_stage(bid, t, P.t2, P.ln2_w + L * 512, P.ln2_b + L * 512, P.h, P.hbf, 1);
    grid.sync();
  }
  // final encoder LN: h -> hbf only
  ln_stage(bid, t, P.h, P.fln_w, P.fln_b, nullptr, P.hbf, 0);
  grid.sync();
  // head MLPs, z-batched over 4 heads: 256 tiles each of 64x128
  gemm_stage<64, 128, 1, 0, 1, 0>(SM, bid, t, P.hbf, P.wm0, P.mlp_b0, nullptr, nullptr, P.z1,
                                  1024, 512, 512, 4, 0, 512 * 512, 512, 1024 * 512);
  grid.sync();
  gemm_stage<64, 128, 1, 0, 1, 0>(SM, bid, t, P.z1, P.wm1, P.mlp_b1, nullptr, nullptr, P.z2,
                                  1024, 512, 512, 4, 1024 * 512, 512 * 512, 512, 1024 * 512);
  grid.sync();
  gemm_stage<64, 128, 0, 1, 1, 0>(SM, bid, t, P.z2, P.wm2, P.mlp_b2, nullptr, P.hf4, P.hb4,
                                  1024, 512, 512, 4, 1024 * 512, 512 * 512, 512, 1024 * 512);
}

// ---------------------------------------------------------------- phase C (unchanged, validated)
__global__ __launch_bounds__(256) void phasec_kernel(const float* __restrict__ subp,
                                                     const unsigned short* __restrict__ objbf,
                                                     const float* __restrict__ vsub,
                                                     const float* __restrict__ vobj,
                                                     float* __restrict__ out) {
  constexpr int ABY = 128 * 64 * 2;
  __shared__ __align__(16) char SMEM[67584];
  char* Asb = SMEM;
  char* Bsb = SMEM + 2 * ABY;
  float* Wl = (float*)(SMEM + 4 * ABY);
  const int t = threadIdx.x;
  const int i = blockIdx.x, b = blockIdx.y;
  const long base_bi = ((long)b * 128 + i) * 512;
  for (int d = t; d < 512; d += 256) Wl[d] = vsub[base_bi + d] * vobj[base_bi + d];

  const int lane = t & 63, wv = t >> 6;
  const int wr = wv >> 1, wc = wv & 1;
  f32x4 acc[4][4] = {};

  int row[4], slot[4];
#pragma unroll
  for (int c = 0; c < 4; ++c) { int id = c * 256 + t; row[c] = id >> 3; slot[c] = id & 7; }

  f32x4 fa[4][2];
  u16x8 rb[4];
  auto load = [&](int kt) {
#pragma unroll
    for (int c = 0; c < 4; ++c) {
      const long g = ((long)b * 128 + row[c]) * 512 + kt + slot[c] * 8;
      fa[c][0] = *(const f32x4*)(subp + g);
      fa[c][1] = *(const f32x4*)(subp + g + 4);
      rb[c] = *(const u16x8*)(objbf + g);
    }
  };
  auto store = [&](int cur, int ktd) {
#pragma unroll
    for (int c = 0; c < 4; ++c) {
      const float* wp = Wl + ktd + slot[c] * 8;
      f32x4 w0 = *(const f32x4*)wp;
      f32x4 w1 = *(const f32x4*)(wp + 4);
      u16x8 oa;
      oa[0] = f2bf(fa[c][0][0] * w0[0]); oa[1] = f2bf(fa[c][0][1] * w0[1]);
      oa[2] = f2bf(fa[c][0][2] * w0[2]); oa[3] = f2bf(fa[c][0][3] * w0[3]);
      oa[4] = f2bf(fa[c][1][0] * w1[0]); oa[5] = f2bf(fa[c][1][1] * w1[1]);
      oa[6] = f2bf(fa[c][1][2] * w1[2]); oa[7] = f2bf(fa[c][1][3] * w1[3]);
      *(u16x8*)(Asb + cur * ABY + swz(row[c], slot[c] * 16)) = oa;
      *(u16x8*)(Bsb + cur * ABY + swz(row[c], slot[c] * 16)) = rb[c];
    }
  };

  __syncthreads();
  load(0);
  store(0, 0);
  load(64);
  __syncthreads();
  for (int ki = 0; ki < 8; ++ki) {
    const int cur = ki & 1;
    if (ki + 1 < 8) store(cur ^ 1, (ki + 1) * 64);
    if (ki + 2 < 8) load((ki + 2) * 64);
#pragma unroll
    for (int kk = 0; kk < 2; ++kk) {
      const int kb = kk * 64 + ((lane >> 4) << 4);
      bf16x8 af[4], bfv[4];
#pragma unroll
      for (int mi = 0; mi < 4; ++mi)
        af[mi] = *(const bf16x8*)(Asb + cur * ABY + swz(wr * 64 + mi * 16 + (lane & 15), kb));
#pragma unroll
      for (int ni = 0; ni < 4; ++ni)
        bfv[ni] = *(const bf16x8*)(Bsb + cur * ABY + swz(wc * 64 + ni * 16 + (lane & 15), kb));
#pragma unroll
      for (int mi = 0; mi < 4; ++mi)
#pragma unroll
        for (int ni = 0; ni < 4; ++ni)
          acc[mi][ni] = __builtin_amdgcn_mfma_f32_16x16x32_bf16(af[mi], bfv[ni], acc[mi][ni], 0, 0, 0);
    }
    __syncthreads();
  }
  float* C = (float*)SMEM;
#pragma unroll
  for (int mi = 0; mi < 4; ++mi)
#pragma unroll
    for (int rr = 0; rr < 4; ++rr) {
      const int j = wr * 64 + mi * 16 + ((lane >> 4) << 2) + rr;
      float* crow = C + j * 132 + wc * 64 + (lane & 15);
#pragma unroll
      for (int ni = 0; ni < 4; ++ni) crow[ni * 16] = acc[mi][ni][rr];
    }
  __syncthreads();
  float* ob = out + ((long)b * 128 + i) * 128 * 128;
  const int cc = (t & 31) * 4, jb = (t >> 5) * 16;
#pragma unroll
  for (int q = 0; q < 16; ++q) {
    const int j = jb + q;
    f32x4 v = *(const f32x4*)(C + j * 132 + cc);
    *(f32x4*)(ob + (long)j * 128 + cc) = v;
  }
}

// ---------------------------------------------------------------- launch
extern "C" void kernel_launch(void* const* d_in, const int* in_sizes, int n_in, void* d_out,
                              int out_size, void* d_ws, size_t ws_size, hipStream_t stream) {
  const float* x          = (const float*)d_in[0];
  const float* attn_in_w  = (const float*)d_in[1];
  const float* attn_in_b  = (const float*)d_in[2];
  const float* attn_out_w = (const float*)d_in[3];
  const float* attn_out_b = (const float*)d_in[4];
  const float* ln1_w = (const float*)d_in[5];
  const float* ln1_b = (const float*)d_in[6];
  const float* ln2_w = (const float*)d_in[7];
  const float* ln2_b = (const float*)d_in[8];
  const float* ff1_w = (const float*)d_in[9];
  const float* ff1_b = (const float*)d_in[10];
  const float* ff2_w = (const float*)d_in[11];
  const float* ff2_b = (const float*)d_in[12];
  const float* fln_w = (const float*)d_in[13];
  const float* fln_b = (const float*)d_in[14];
  const float* mlp_w0 = (const float*)d_in[15];
  const float* mlp_b0 = (const float*)d_in[16];
  const float* mlp_w1 = (const float*)d_in[17];
  const float* mlp_b1 = (const float*)d_in[18];
  const float* mlp_w2 = (const float*)d_in[19];
  const float* mlp_b2 = (const float*)d_in[20];
  float* out = (float*)d_out;
  (void)in_sizes; (void)n_in; (void)out_size; (void)ws_size;

  char* ws = (char*)d_ws;
  size_t off = 0;
  auto alloc = [&](size_t bytes) -> void* {
    void* p = (void*)(ws + off);
    off += (bytes + 255) & ~(size_t)255;
    return p;
  };
  unsigned short* wq  = (unsigned short*)alloc((size_t)3 * 1536 * 512 * 2);
  unsigned short* wo  = (unsigned short*)alloc((size_t)3 * 512 * 512 * 2);
  unsigned short* wf1 = (unsigned short*)alloc((size_t)3 * 2048 * 512 * 2);
  unsigned short* wf2 = (unsigned short*)alloc((size_t)3 * 512 * 2048 * 2);
  unsigned short* wm0 = (unsigned short*)alloc((size_t)4 * 512 * 512 * 2);
  unsigned short* wm1 = (unsigned short*)alloc((size_t)4 * 512 * 512 * 2);
  unsigned short* wm2 = (unsigned short*)alloc((size_t)4 * 512 * 512 * 2);
  float* h            = (float*)alloc((size_t)1024 * 512 * 4);
  unsigned short* hbf = (unsigned short*)alloc((size_t)1024 * 512 * 2);
  unsigned short* t1  = (unsigned short*)alloc((size_t)1024 * 2048 * 2);
  float* t2           = (float*)alloc((size_t)1024 * 512 * 4);
  unsigned short* ao  = (unsigned short*)alloc((size_t)1024 * 512 * 2);
  unsigned short* z1  = (unsigned short*)alloc((size_t)4 * 1024 * 512 * 2);
  unsigned short* z2  = (unsigned short*)alloc((size_t)4 * 1024 * 512 * 2);
  float* hf4          = (float*)alloc((size_t)4 * 1024 * 512 * 4);
  unsigned short* hb4 = (unsigned short*)alloc((size_t)4 * 1024 * 512 * 2);

  CvtJobs J;
  for (int k = 0; k < 8; ++k) J.df[k] = nullptr;
  J.s[0] = attn_in_w;  J.d[0] = wq;  J.n[0] = 3 * 1536 * 512;
  J.s[1] = attn_out_w; J.d[1] = wo;  J.n[1] = 3 * 512 * 512;
  J.s[2] = ff1_w;      J.d[2] = wf1; J.n[2] = 3 * 2048 * 512;
  J.s[3] = ff2_w;      J.d[3] = wf2; J.n[3] = 3 * 512 * 2048;
  J.s[4] = mlp_w0;     J.d[4] = wm0; J.n[4] = 4 * 512 * 512;
  J.s[5] = mlp_w1;     J.d[5] = wm1; J.n[5] = 4 * 512 * 512;
  J.s[6] = mlp_w2;     J.d[6] = wm2; J.n[6] = 4 * 512 * 512;
  J.s[7] = x;          J.d[7] = hbf; J.n[7] = 1024 * 512; J.df[7] = h;
  cvtw_kernel<<<dim3(512, 8), 256, 0, stream>>>(J);

  Params P;
  P.attn_in_b = attn_in_b; P.attn_out_b = attn_out_b;
  P.ln1_w = ln1_w; P.ln1_b = ln1_b; P.ln2_w = ln2_w; P.ln2_b = ln2_b;
  P.ff1_b = ff1_b; P.ff2_b = ff2_b; P.fln_w = fln_w; P.fln_b = fln_b;
  P.mlp_b0 = mlp_b0; P.mlp_b1 = mlp_b1; P.mlp_b2 = mlp_b2;
  P.wq = wq; P.wo = wo; P.wf1 = wf1; P.wf2 = wf2;
  P.wm0 = wm0; P.wm1 = wm1; P.wm2 = wm2;
  P.h = h; P.t2 = t2; P.hf4 = hf4;
  P.hbf = hbf; P.t1 = t1; P.ao = ao; P.z1 = z1; P.z2 = z2; P.hb4 = hb4;
  void* args[] = {&P};
  hipLaunchCooperativeKernel((void*)fused_kernel, dim3(GRID), dim3(BLOCK), args, 0, stream);

  phasec_kernel<<<dim3(128, 8), 256, 0, stream>>>(
      hf4, hb4 + 1 * 1024 * 512, hf4 + 2L * 1024 * 512, hf4 + 3L * 1024 * 512, out);
}

// Round 7
// 388.753 us; speedup vs baseline: 3.2434x; 2.7896x over previous
//
#include <hip/hip_runtime.h>
#include <hip/hip_bf16.h>

#define DEV __device__ __forceinline__

typedef __attribute__((ext_vector_type(8))) short bf16x8;
typedef __attribute__((ext_vector_type(8))) unsigned short u16x8;
typedef __attribute__((ext_vector_type(4))) float f32x4;

DEV unsigned short f2bf(float f) {
  return __builtin_bit_cast(unsigned short, __float2bfloat16(f));
}
DEV float bf2f(unsigned short h) { return __uint_as_float(((unsigned int)h) << 16); }

// LDS swizzle for BK=64 tiles (128B rows): XOR 16B-slot with (row&7).
DEV int swz(int row, int byteoff) { return row * 128 + (byteoff ^ ((row & 7) << 4)); }

// ---------------------------------------------------------------- cvt fp32->bf16 (8 segments)
struct CvtJobs { const float* s[8]; unsigned short* d[8]; int n[8]; };
__global__ void cvtw_kernel(CvtJobs J) {
  const int seg = blockIdx.y;
  const float* __restrict__ src = J.s[seg];
  unsigned short* __restrict__ dst = J.d[seg];
  const int n = J.n[seg];
  long i = ((long)blockIdx.x * blockDim.x + threadIdx.x) * 8;
  long stride = (long)gridDim.x * blockDim.x * 8;
  for (; i < n; i += stride) {
    f32x4 a = *(const f32x4*)(src + i);
    f32x4 b = *(const f32x4*)(src + i + 4);
    u16x8 o;
    o[0] = f2bf(a[0]); o[1] = f2bf(a[1]); o[2] = f2bf(a[2]); o[3] = f2bf(a[3]);
    o[4] = f2bf(b[0]); o[5] = f2bf(b[1]); o[6] = f2bf(b[2]); o[7] = f2bf(b[3]);
    *(u16x8*)(dst + i) = o;
  }
}

// ---------------------------------------------------------------- GEMM (generic, LN-fusing)
// Y[m,n] = act( X'[m,:]·W[n,:] + bias[n] [+ res'[m,n]] )
// X' = ALN ? LN(Xf; sA,gA,bA) applied at staging (K=512) : Xb (bf16).
// res' = RES ? (RLN ? LN(resf; sR,gR,bR) : resf) : 0   (res stride 512).
// STATS: accumulate per-row (sum,sumsq) of the output u into stats via atomics.
// 256 threads, 4 waves as 2x2; wave = (BM/2)x(BN/2); BK=64 dbuf pipeline.
template <int BM, int BN, int ALN, int RES, int RLN, int ACT, int STATS, int OUTF32, int OUTBF>
__global__ __launch_bounds__(256) void gemm2_kernel(
    const unsigned short* __restrict__ Xb, const float* __restrict__ Xf,
    const float* __restrict__ sA, const float* __restrict__ gA, const float* __restrict__ bA,
    const unsigned short* __restrict__ W, const float* __restrict__ bias,
    const float* __restrict__ resf, const float* __restrict__ sR,
    const float* __restrict__ gR, const float* __restrict__ bR,
    float* __restrict__ Yf, unsigned short* __restrict__ Ybf, float* __restrict__ stats,
    int M, int N, int K, long xbs, long wbs, long bbs, long ybs) {
  constexpr int CA = BM / 32, CB = BN / 32;
  constexpr int ABY = BM * 64 * 2, BBY = BN * 64 * 2;
  constexpr int MI = BM / 32, NI = BN / 32;
  __shared__ __align__(16) char Asb[2 * ABY];
  __shared__ __align__(16) char Bsb[2 * BBY];
  const int t = threadIdx.x;
  const int bn = blockIdx.x, bm = blockIdx.y, bz = blockIdx.z;
  const int lane = t & 63, wv = t >> 6, wr = wv >> 1, wc = wv & 1;

  int rowA[CA], slotA[CA], rowB[CB], slotB[CB];
#pragma unroll
  for (int c = 0; c < CA; ++c) { int id = c * 256 + t; rowA[c] = id >> 3; slotA[c] = id & 7; }
#pragma unroll
  for (int c = 0; c < CB; ++c) { int id = c * 256 + t; rowB[c] = id >> 3; slotB[c] = id & 7; }

  // LN params for the A rows this thread stages (constant across K-steps)
  float mA[CA], iA[CA];
  if (ALN) {
#pragma unroll
    for (int c = 0; c < CA; ++c) {
      const int gm = bm * BM + rowA[c];
      const float s = sA[2 * gm], q = sA[2 * gm + 1];
      mA[c] = s * (1.f / 512.f);
      iA[c] = rsqrtf(q * (1.f / 512.f) - mA[c] * mA[c] + 1e-5f);
    }
  }

  f32x4 acc[MI][NI];
#pragma unroll
  for (int mi = 0; mi < MI; ++mi)
#pragma unroll
    for (int ni = 0; ni < NI; ++ni) acc[mi][ni] = f32x4{0.f, 0.f, 0.f, 0.f};

  u16x8 ra[CA], rb[CB];
  f32x4 raf[CA][2];
  auto load = [&](int kt) {
#pragma unroll
    for (int c = 0; c < CA; ++c) {
      if (ALN) {
        const float* p = Xf + (long)(bm * BM + rowA[c]) * K + kt + slotA[c] * 8;
        raf[c][0] = *(const f32x4*)p;
        raf[c][1] = *(const f32x4*)(p + 4);
      } else {
        ra[c] = *(const u16x8*)(Xb + (long)bz * xbs + (long)(bm * BM + rowA[c]) * K + kt + slotA[c] * 8);
      }
    }
#pragma unroll
    for (int c = 0; c < CB; ++c)
      rb[c] = *(const u16x8*)(W + (long)bz * wbs + (long)(bn * BN + rowB[c]) * K + kt + slotB[c] * 8);
  };
  auto store = [&](int cur, int kt) {
#pragma unroll
    for (int c = 0; c < CA; ++c) {
      if (ALN) {
        const int col = kt + slotA[c] * 8;
        f32x4 g0 = *(const f32x4*)(gA + col), g1 = *(const f32x4*)(gA + col + 4);
        f32x4 b0 = *(const f32x4*)(bA + col), b1 = *(const f32x4*)(bA + col + 4);
        u16x8 o;
#pragma unroll
        for (int j = 0; j < 4; ++j) o[j] = f2bf((raf[c][0][j] - mA[c]) * iA[c] * g0[j] + b0[j]);
#pragma unroll
        for (int j = 0; j < 4; ++j) o[4 + j] = f2bf((raf[c][1][j] - mA[c]) * iA[c] * g1[j] + b1[j]);
        *(u16x8*)(Asb + cur * ABY + swz(rowA[c], slotA[c] * 16)) = o;
      } else {
        *(u16x8*)(Asb + cur * ABY + swz(rowA[c], slotA[c] * 16)) = ra[c];
      }
    }
#pragma unroll
    for (int c = 0; c < CB; ++c)
      *(u16x8*)(Bsb + cur * BBY + swz(rowB[c], slotB[c] * 16)) = rb[c];
  };

  const int NT = K >> 6;
  load(0);
  store(0, 0);
  load(64);
  __syncthreads();
  for (int ki = 0; ki < NT; ++ki) {
    const int cur = ki & 1;
    if (ki + 1 < NT) store(cur ^ 1, (ki + 1) << 6);
    if (ki + 2 < NT) load((ki + 2) << 6);
#pragma unroll
    for (int kk = 0; kk < 2; ++kk) {
      const int kb = kk * 64 + ((lane >> 4) << 4);
      bf16x8 af[MI], bfv[NI];
#pragma unroll
      for (int mi = 0; mi < MI; ++mi)
        af[mi] = *(const bf16x8*)(Asb + cur * ABY + swz(wr * (BM / 2) + mi * 16 + (lane & 15), kb));
#pragma unroll
      for (int ni = 0; ni < NI; ++ni)
        bfv[ni] = *(const bf16x8*)(Bsb + cur * BBY + swz(wc * (BN / 2) + ni * 16 + (lane & 15), kb));
#pragma unroll
      for (int mi = 0; mi < MI; ++mi)
#pragma unroll
        for (int ni = 0; ni < NI; ++ni)
          acc[mi][ni] = __builtin_amdgcn_mfma_f32_16x16x32_bf16(af[mi], bfv[ni], acc[mi][ni], 0, 0, 0);
    }
    __syncthreads();
  }

  // epilogue
#pragma unroll
  for (int mi = 0; mi < MI; ++mi) {
#pragma unroll
    for (int rr = 0; rr < 4; ++rr) {
      const int gm = bm * BM + wr * (BM / 2) + mi * 16 + ((lane >> 4) << 2) + rr;
      float mR, iR;
      if (RES && RLN) {
        const float s = sR[2 * gm], q = sR[2 * gm + 1];
        mR = s * (1.f / 512.f);
        iR = rsqrtf(q * (1.f / 512.f) - mR * mR + 1e-5f);
      }
      float srow = 0.f, qrow = 0.f;
#pragma unroll
      for (int ni = 0; ni < NI; ++ni) {
        const int gn = bn * BN + wc * (BN / 2) + ni * 16 + (lane & 15);
        float v = acc[mi][ni][rr] + bias[(long)bz * bbs + gn];
        if (RES) {
          float r = resf[(long)gm * 512 + gn];
          if (RLN) r = (r - mR) * iR * gR[gn] + bR[gn];
          v += r;
        }
        if (ACT) v = fmaxf(v, 0.f);
        if (STATS) { srow += v; qrow += v * v; }
        const long o = (long)bz * ybs + (long)gm * N + gn;
        if (OUTF32) Yf[o] = v;
        if (OUTBF) Ybf[o] = f2bf(v);
      }
      if (STATS) {
#pragma unroll
        for (int msk = 1; msk < 16; msk <<= 1) {
          srow += __shfl_xor(srow, msk, 64);
          qrow += __shfl_xor(qrow, msk, 64);
        }
        if ((lane & 15) == 0) {
          atomicAdd(&stats[2 * gm], srow);
          atomicAdd(&stats[2 * gm + 1], qrow);
        }
      }
    }
  }
}

// ---------------------------------------------------------------- attention (standalone, validated R1)
__global__ __launch_bounds__(256) void attn_kernel(const unsigned short* __restrict__ qkv,
                                                   unsigned short* __restrict__ o) {
  __shared__ float P[512];  // [h][l][m]
  const int s = blockIdx.x;
  const int t = threadIdx.x;
#pragma unroll
  for (int rep = 0; rep < 2; ++rep) {
    const int idx = t + rep * 256;
    const int h = idx >> 6, l = (idx >> 3) & 7, m = idx & 7;
    const unsigned short* qp = qkv + (long)(l * 128 + s) * 1536 + h * 64;
    const unsigned short* kp = qkv + (long)(m * 128 + s) * 1536 + 512 + h * 64;
    float acc = 0.f;
#pragma unroll
    for (int c = 0; c < 64; c += 8) {
      u16x8 q8 = *(const u16x8*)(qp + c);
      u16x8 k8 = *(const u16x8*)(kp + c);
#pragma unroll
      for (int j = 0; j < 8; ++j) acc += bf2f(q8[j]) * bf2f(k8[j]);
    }
    P[idx] = acc * 0.125f;
  }
  __syncthreads();
  if (t < 64) {
    const int base = t * 8;
    float mx = -1e30f;
#pragma unroll
    for (int m = 0; m < 8; ++m) mx = fmaxf(mx, P[base + m]);
    float e[8], sum = 0.f;
#pragma unroll
    for (int m = 0; m < 8; ++m) { e[m] = expf(P[base + m] - mx); sum += e[m]; }
    const float inv = 1.f / sum;
#pragma unroll
    for (int m = 0; m < 8; ++m) P[base + m] = e[m] * inv;
  }
  __syncthreads();
#pragma unroll
  for (int rep = 0; rep < 16; ++rep) {
    const int idx = t + rep * 256;  // l*512 + h*64 + d
    const int d = idx & 63, h = (idx >> 6) & 7, l = idx >> 9;
    float acc = 0.f;
#pragma unroll
    for (int m = 0; m < 8; ++m)
      acc += P[h * 64 + l * 8 + m] * bf2f(qkv[(long)(m * 128 + s) * 1536 + 1024 + h * 64 + d]);
    o[(long)(l * 128 + s) * 512 + h * 64 + d] = f2bf(acc);
  }
}

// ---------------------------------------------------------------- last LN2 -> FLN chained
// in: t2 (pre-LN u), S (stats of u). out bf16 = FLN(LN2(u)). 4 rows/block (wave each).
__global__ __launch_bounds__(256) void lastln_kernel(const float* __restrict__ t2,
                                                     const float* __restrict__ S,
                                                     const float* __restrict__ g2,
                                                     const float* __restrict__ b2,
                                                     const float* __restrict__ gf,
                                                     const float* __restrict__ bf_,
                                                     unsigned short* __restrict__ out) {
  const int t = threadIdx.x, lane = t & 63, wv = t >> 6;
  const int row = blockIdx.x * 4 + wv;
  const float* p = t2 + (long)row * 512 + lane * 8;
  f32x4 a = *(const f32x4*)p;
  f32x4 c = *(const f32x4*)(p + 4);
  const float s0 = S[2 * row], q0 = S[2 * row + 1];
  const float m1 = s0 * (1.f / 512.f);
  const float i1 = rsqrtf(q0 * (1.f / 512.f) - m1 * m1 + 1e-5f);
  float v[8];
  const float* g2p = g2 + lane * 8;
  const float* b2p = b2 + lane * 8;
#pragma unroll
  for (int j = 0; j < 4; ++j) v[j] = (a[j] - m1) * i1 * g2p[j] + b2p[j];
#pragma unroll
  for (int j = 0; j < 4; ++j) v[4 + j] = (c[j] - m1) * i1 * g2p[4 + j] + b2p[4 + j];
  float s = 0.f, q = 0.f;
#pragma unroll
  for (int j = 0; j < 8; ++j) { s += v[j]; q += v[j] * v[j]; }
#pragma unroll
  for (int msk = 32; msk; msk >>= 1) { s += __shfl_xor(s, msk, 64); q += __shfl_xor(q, msk, 64); }
  const float m2 = s * (1.f / 512.f);
  const float i2 = rsqrtf(q * (1.f / 512.f) - m2 * m2 + 1e-5f);
  const float* gfp = gf + lane * 8;
  const float* bfp = bf_ + lane * 8;
  u16x8 o;
#pragma unroll
  for (int j = 0; j < 8; ++j) o[j] = f2bf((v[j] - m2) * i2 * gfp[j] + bfp[j]);
  *(u16x8*)(out + (long)row * 512 + lane * 8) = o;
}

// ---------------------------------------------------------------- phase C (validated)
__global__ __launch_bounds__(256) void phasec_kernel(const float* __restrict__ subp,
                                                     const unsigned short* __restrict__ objbf,
                                                     const float* __restrict__ vsub,
                                                     const float* __restrict__ vobj,
                                                     float* __restrict__ out) {
  constexpr int ABY = 128 * 64 * 2;
  __shared__ __align__(16) char SMEM[67584];
  char* Asb = SMEM;
  char* Bsb = SMEM + 2 * ABY;
  float* Wl = (float*)(SMEM + 4 * ABY);
  const int t = threadIdx.x;
  const int i = blockIdx.x, b = blockIdx.y;
  const long base_bi = ((long)b * 128 + i) * 512;
  for (int d = t; d < 512; d += 256) Wl[d] = vsub[base_bi + d] * vobj[base_bi + d];

  const int lane = t & 63, wv = t >> 6;
  const int wr = wv >> 1, wc = wv & 1;
  f32x4 acc[4][4] = {};

  int row[4], slot[4];
#pragma unroll
  for (int c = 0; c < 4; ++c) { int id = c * 256 + t; row[c] = id >> 3; slot[c] = id & 7; }

  f32x4 fa[4][2];
  u16x8 rb[4];
  auto load = [&](int kt) {
#pragma unroll
    for (int c = 0; c < 4; ++c) {
      const long g = ((long)b * 128 + row[c]) * 512 + kt + slot[c] * 8;
      fa[c][0] = *(const f32x4*)(subp + g);
      fa[c][1] = *(const f32x4*)(subp + g + 4);
      rb[c] = *(const u16x8*)(objbf + g);
    }
  };
  auto store = [&](int cur, int ktd) {
#pragma unroll
    for (int c = 0; c < 4; ++c) {
      const float* wp = Wl + ktd + slot[c] * 8;
      f32x4 w0 = *(const f32x4*)wp;
      f32x4 w1 = *(const f32x4*)(wp + 4);
      u16x8 oa;
      oa[0] = f2bf(fa[c][0][0] * w0[0]); oa[1] = f2bf(fa[c][0][1] * w0[1]);
      oa[2] = f2bf(fa[c][0][2] * w0[2]); oa[3] = f2bf(fa[c][0][3] * w0[3]);
      oa[4] = f2bf(fa[c][1][0] * w1[0]); oa[5] = f2bf(fa[c][1][1] * w1[1]);
      oa[6] = f2bf(fa[c][1][2] * w1[2]); oa[7] = f2bf(fa[c][1][3] * w1[3]);
      *(u16x8*)(Asb + cur * ABY + swz(row[c], slot[c] * 16)) = oa;
      *(u16x8*)(Bsb + cur * ABY + swz(row[c], slot[c] * 16)) = rb[c];
    }
  };

  __syncthreads();
  load(0);
  store(0, 0);
  load(64);
  __syncthreads();
  for (int ki = 0; ki < 8; ++ki) {
    const int cur = ki & 1;
    if (ki + 1 < 8) store(cur ^ 1, (ki + 1) * 64);
    if (ki + 2 < 8) load((ki + 2) * 64);
#pragma unroll
    for (int kk = 0; kk < 2; ++kk) {
      const int kb = kk * 64 + ((lane >> 4) << 4);
      bf16x8 af[4], bfv[4];
#pragma unroll
      for (int mi = 0; mi < 4; ++mi)
        af[mi] = *(const bf16x8*)(Asb + cur * ABY + swz(wr * 64 + mi * 16 + (lane & 15), kb));
#pragma unroll
      for (int ni = 0; ni < 4; ++ni)
        bfv[ni] = *(const bf16x8*)(Bsb + cur * ABY + swz(wc * 64 + ni * 16 + (lane & 15), kb));
#pragma unroll
      for (int mi = 0; mi < 4; ++mi)
#pragma unroll
        for (int ni = 0; ni < 4; ++ni)
          acc[mi][ni] = __builtin_amdgcn_mfma_f32_16x16x32_bf16(af[mi], bfv[ni], acc[mi][ni], 0, 0, 0);
    }
    __syncthreads();
  }
  float* C = (float*)SMEM;
#pragma unroll
  for (int mi = 0; mi < 4; ++mi)
#pragma unroll
    for (int rr = 0; rr < 4; ++rr) {
      const int j = wr * 64 + mi * 16 + ((lane >> 4) << 2) + rr;
      float* crow = C + j * 132 + wc * 64 + (lane & 15);
#pragma unroll
      for (int ni = 0; ni < 4; ++ni) crow[ni * 16] = acc[mi][ni][rr];
    }
  __syncthreads();
  float* ob = out + ((long)b * 128 + i) * 128 * 128;
  const int cc = (t & 31) * 4, jb = (t >> 5) * 16;
#pragma unroll
  for (int q = 0; q < 16; ++q) {
    const int j = jb + q;
    f32x4 v = *(const f32x4*)(C + j * 132 + cc);
    *(f32x4*)(ob + (long)j * 128 + cc) = v;
  }
}

// ---------------------------------------------------------------- launch
extern "C" void kernel_launch(void* const* d_in, const int* in_sizes, int n_in, void* d_out,
                              int out_size, void* d_ws, size_t ws_size, hipStream_t stream) {
  const float* x          = (const float*)d_in[0];
  const float* attn_in_w  = (const float*)d_in[1];
  const float* attn_in_b  = (const float*)d_in[2];
  const float* attn_out_w = (const float*)d_in[3];
  const float* attn_out_b = (const float*)d_in[4];
  const float* ln1_w = (const float*)d_in[5];
  const float* ln1_b = (const float*)d_in[6];
  const float* ln2_w = (const float*)d_in[7];
  const float* ln2_b = (const float*)d_in[8];
  const float* ff1_w = (const float*)d_in[9];
  const float* ff1_b = (const float*)d_in[10];
  const float* ff2_w = (const float*)d_in[11];
  const float* ff2_b = (const float*)d_in[12];
  const float* fln_w = (const float*)d_in[13];
  const float* fln_b = (const float*)d_in[14];
  const float* mlp_w0 = (const float*)d_in[15];
  const float* mlp_b0 = (const float*)d_in[16];
  const float* mlp_w1 = (const float*)d_in[17];
  const float* mlp_b1 = (const float*)d_in[18];
  const float* mlp_w2 = (const float*)d_in[19];
  const float* mlp_b2 = (const float*)d_in[20];
  float* out = (float*)d_out;
  (void)in_sizes; (void)n_in; (void)out_size; (void)ws_size;

  char* ws = (char*)d_ws;
  size_t off = 0;
  auto alloc = [&](size_t bytes) -> void* {
    void* p = (void*)(ws + off);
    off += (bytes + 255) & ~(size_t)255;
    return p;
  };
  float* stats        = (float*)alloc((size_t)6 * 1024 * 2 * 4);  // 6 LN instances
  unsigned short* wq  = (unsigned short*)alloc((size_t)3 * 1536 * 512 * 2);
  unsigned short* wo  = (unsigned short*)alloc((size_t)3 * 512 * 512 * 2);
  unsigned short* wf1 = (unsigned short*)alloc((size_t)3 * 2048 * 512 * 2);
  unsigned short* wf2 = (unsigned short*)alloc((size_t)3 * 512 * 2048 * 2);
  unsigned short* wm0 = (unsigned short*)alloc((size_t)4 * 512 * 512 * 2);
  unsigned short* wm1 = (unsigned short*)alloc((size_t)4 * 512 * 512 * 2);
  unsigned short* wm2 = (unsigned short*)alloc((size_t)4 * 512 * 512 * 2);
  unsigned short* hbf0 = (unsigned short*)alloc((size_t)1024 * 512 * 2);
  unsigned short* t1  = (unsigned short*)alloc((size_t)1024 * 2048 * 2);
  unsigned short* ao  = (unsigned short*)alloc((size_t)1024 * 512 * 2);
  float* t2a          = (float*)alloc((size_t)1024 * 512 * 4);
  float* t2b          = (float*)alloc((size_t)1024 * 512 * 4);
  unsigned short* hbfH = (unsigned short*)alloc((size_t)1024 * 512 * 2);
  unsigned short* z1  = (unsigned short*)alloc((size_t)4 * 1024 * 512 * 2);
  unsigned short* z2  = (unsigned short*)alloc((size_t)4 * 1024 * 512 * 2);
  float* hf4          = (float*)alloc((size_t)4 * 1024 * 512 * 4);
  unsigned short* hb4 = (unsigned short*)alloc((size_t)4 * 1024 * 512 * 2);

  hipMemsetAsync(stats, 0, (size_t)6 * 1024 * 2 * 4, stream);

  CvtJobs J;
  J.s[0] = attn_in_w;  J.d[0] = wq;  J.n[0] = 3 * 1536 * 512;
  J.s[1] = attn_out_w; J.d[1] = wo;  J.n[1] = 3 * 512 * 512;
  J.s[2] = ff1_w;      J.d[2] = wf1; J.n[2] = 3 * 2048 * 512;
  J.s[3] = ff2_w;      J.d[3] = wf2; J.n[3] = 3 * 512 * 2048;
  J.s[4] = mlp_w0;     J.d[4] = wm0; J.n[4] = 4 * 512 * 512;
  J.s[5] = mlp_w1;     J.d[5] = wm1; J.n[5] = 4 * 512 * 512;
  J.s[6] = mlp_w2;     J.d[6] = wm2; J.n[6] = 4 * 512 * 512;
  J.s[7] = x;          J.d[7] = hbf0; J.n[7] = 1024 * 512;
  cvtw_kernel<<<dim3(512, 8), 256, 0, stream>>>(J);

  for (int L = 0; L < 3; ++L) {
    float* Sout = stats + (2 * L) * 2048;      // outproj stats of layer L
    float* Sff  = stats + (2 * L + 1) * 2048;  // ff2 stats of layer L
    const float* Sprev = stats + (2 * L - 1) * 2048;  // ff2 stats of layer L-1 (L>=1)
    // ---- qkv
    if (L == 0)
      gemm2_kernel<64, 128, 0, 0, 0, 0, 0, 0, 1><<<dim3(12, 16), 256, 0, stream>>>(
          hbf0, nullptr, nullptr, nullptr, nullptr, wq, attn_in_b, nullptr, nullptr, nullptr,
          nullptr, nullptr, t1, nullptr, 1024, 1536, 512, 0, 0, 0, 0);
    else
      gemm2_kernel<64, 128, 1, 0, 0, 0, 0, 0, 1><<<dim3(12, 16), 256, 0, stream>>>(
          nullptr, t2b, Sprev, ln2_w + (L - 1) * 512, ln2_b + (L - 1) * 512,
          wq + (long)L * 1536 * 512, attn_in_b + L * 1536, nullptr, nullptr, nullptr,
          nullptr, nullptr, t1, nullptr, 1024, 1536, 512, 0, 0, 0, 0);
    // ---- attention
    attn_kernel<<<128, 256, 0, stream>>>(t1, ao);
    // ---- outproj + residual (+stats)
    if (L == 0)
      gemm2_kernel<32, 64, 0, 1, 0, 0, 1, 1, 0><<<dim3(8, 32), 256, 0, stream>>>(
          ao, nullptr, nullptr, nullptr, nullptr, wo, attn_out_b, x, nullptr, nullptr, nullptr,
          t2a, nullptr, Sout, 1024, 512, 512, 0, 0, 0, 0);
    else
      gemm2_kernel<32, 64, 0, 1, 1, 0, 1, 1, 0><<<dim3(8, 32), 256, 0, stream>>>(
          ao, nullptr, nullptr, nullptr, nullptr, wo + (long)L * 512 * 512, attn_out_b + L * 512,
          t2b, Sprev, ln2_w + (L - 1) * 512, ln2_b + (L - 1) * 512,
          t2a, nullptr, Sout, 1024, 512, 512, 0, 0, 0, 0);
    // ---- ff1 (LN1 on load, relu)
    gemm2_kernel<64, 128, 1, 0, 0, 1, 0, 0, 1><<<dim3(16, 16), 256, 0, stream>>>(
        nullptr, t2a, Sout, ln1_w + L * 512, ln1_b + L * 512,
        wf1 + (long)L * 2048 * 512, ff1_b + L * 2048, nullptr, nullptr, nullptr, nullptr,
        nullptr, t1, nullptr, 1024, 2048, 512, 0, 0, 0, 0);
    // ---- ff2 + residual LN1(t2a) (+stats)
    gemm2_kernel<32, 64, 0, 1, 1, 0, 1, 1, 0><<<dim3(8, 32), 256, 0, stream>>>(
        t1, nullptr, nullptr, nullptr, nullptr, wf2 + (long)L * 512 * 2048, ff2_b + L * 512,
        t2a, Sout, ln1_w + L * 512, ln1_b + L * 512,
        t2b, nullptr, Sff, 1024, 512, 2048, 0, 0, 0, 0);
  }
  // ---- last LN2 -> final LN, writes bf16 head input
  lastln_kernel<<<256, 256, 0, stream>>>(t2b, stats + 5 * 2048, ln2_w + 2 * 512, ln2_b + 2 * 512,
                                         fln_w, fln_b, hbfH);
  // ---- head MLPs (z = 4 heads)
  gemm2_kernel<64, 128, 0, 0, 0, 1, 0, 0, 1><<<dim3(4, 16, 4), 256, 0, stream>>>(
      hbfH, nullptr, nullptr, nullptr, nullptr, wm0, mlp_b0, nullptr, nullptr, nullptr, nullptr,
      nullptr, z1, nullptr, 1024, 512, 512, 0, 512 * 512, 512, 1024 * 512);
  gemm2_kernel<64, 128, 0, 0, 0, 1, 0, 0, 1><<<dim3(4, 16, 4), 256, 0, stream>>>(
      z1, nullptr, nullptr, nullptr, nullptr, wm1, mlp_b1, nullptr, nullptr, nullptr, nullptr,
      nullptr, z2, nullptr, 1024, 512, 512, 1024 * 512, 512 * 512, 512, 1024 * 512);
  gemm2_kernel<64, 128, 0, 0, 0, 0, 0, 1, 1><<<dim3(4, 16, 4), 256, 0, stream>>>(
      z2, nullptr, nullptr, nullptr, nullptr, wm2, mlp_b2, nullptr, nullptr, nullptr, nullptr,
      hf4, hb4, nullptr, 1024, 512, 512, 1024 * 512, 512 * 512, 512, 1024 * 512);

  // heads: 0=sub, 1=obj, 2=verb_sub, 3=verb_obj
  phasec_kernel<<<dim3(128, 8), 256, 0, stream>>>(
      hf4, hb4 + 1 * 1024 * 512, hf4 + 2L * 1024 * 512, hf4 + 3L * 1024 * 512, out);
}